// Round 10
// baseline (7119.707 us; speedup 1.0000x reference)
//
#include <hip/hip_runtime.h>

// AttentionRnnBlock: N=16, T=2048, H=512.
// q|k|v = cat(x_t,h_t) @ W?.T + b? ; w=sigmoid(q*k); h' = (1-w)h + w tanh(v)
//
// Persistent cooperative kernel, 256 WGs x 512 threads, 1 WG/CU.
// 8 groups x 32 WGs; group g owns batches {2g,2g+1}.
//
// ROUND-10 STRUCTURE: the two batches are independent recurrences -> run
// them as STAGGERED PIPELINE PHASES. Phase A (batch 2g) and phase B (2g+1)
// each have their own spin/stage/barrier/compute/store; batch A's
// store->propagate->detect latency (~1us, invariant across rounds 4-8's
// sync mechanisms) hides under phase B's ~1100cy of compute, and vice
// versa. Poll words for each phase are issued at the END of the other
// phase (first-poll-early).
//
// Exchange protocol = round-8-PROVEN: parity double-buffered tagged words
// ex[t&1][g][batch*512+j] = (t<<32)|float_bits, relaxed agent atomics
// (rounds 7/9 both hung on "cleverer" schemes; never again bet a round on
// an unverifiable cache-path assumption). One word per thread per phase.
// WAR chain per batch: slot[p] next overwritten at t+2, gated through the
// writer's t+1 spin -> reader's WG's t+1 tags -> reader's t consume.
//
// Weights: 96 floats/thread in AGPRs via v_accvgpr_write/read (round 6).
#define N_B 16
#define T_S 2048
#define H_D 512
#define TH_F ((size_t)T_S * H_D)
#define NTH ((size_t)N_B * TH_F)
#define NGROUP 8
#define WPG 32
#define THREADS 512
#define EXG 1024                 // words per group per parity
#define EXP_W (NGROUP * EXG)     // words per parity plane

#define STASH(dst, src) asm volatile("v_accvgpr_write_b32 %0, %1" : "=a"(dst) : "v"(src))
#define FETCH(dst, src) asm volatile("v_accvgpr_read_b32 %0, %1" : "=v"(dst) : "a"(src))

__global__ __launch_bounds__(THREADS, 1) void rnn_persist(
    const float* __restrict__ x,
    const float* __restrict__ hidden,
    const float* __restrict__ Wq, const float* __restrict__ bq,
    const float* __restrict__ Wk, const float* __restrict__ bk,
    const float* __restrict__ Wv, const float* __restrict__ bv,
    float* __restrict__ out,
    unsigned long long* __restrict__ ex)
{
    const int tid  = threadIdx.x;
    const int lane = tid & 63;
    const int wv   = tid >> 6;          // wave 0..7
    const int g    = blockIdx.x & 7;    // group
    const int wm   = blockIdx.x >> 3;   // member 0..31
    const int b0 = 2 * g, b1 = 2 * g + 1;
    const int jA = wm * 16 + 2 * wv;

    __shared__ __align__(16) float hs[2][2][H_D];   // [parity][batch][H], 8 KB

    // ---- load weights once, stash all 96 floats into AGPRs
    float awx[2][3][8], awh[2][3][8];
    #pragma unroll
    for (int r = 0; r < 2; ++r) {
        const int j = jA + r;
        #pragma unroll
        for (int m = 0; m < 3; ++m) {
            const float* W = (m == 0) ? Wq : (m == 1) ? Wk : Wv;
            const float* base = W + (size_t)j * 1024 + lane * 8;
            float4 x0 = *(const float4*)(base);
            float4 x1 = *(const float4*)(base + 4);
            float4 h0 = *(const float4*)(base + 512);
            float4 h1 = *(const float4*)(base + 516);
            STASH(awx[r][m][0], x0.x); STASH(awx[r][m][1], x0.y);
            STASH(awx[r][m][2], x0.z); STASH(awx[r][m][3], x0.w);
            STASH(awx[r][m][4], x1.x); STASH(awx[r][m][5], x1.y);
            STASH(awx[r][m][6], x1.z); STASH(awx[r][m][7], x1.w);
            STASH(awh[r][m][0], h0.x); STASH(awh[r][m][1], h0.y);
            STASH(awh[r][m][2], h0.z); STASH(awh[r][m][3], h0.w);
            STASH(awh[r][m][4], h1.x); STASH(awh[r][m][5], h1.y);
            STASH(awh[r][m][6], h1.z); STASH(awh[r][m][7], h1.w);
        }
    }

    // writer lanes 0,1: row jw = jA + lane; each holds h_old for BOTH batches
    const int jw = jA + (lane & 1);
    const float bqw = bq[jw], bkw = bk[jw], bvw = bv[jw];
    float hoA = hidden[b0 * H_D + jw];
    float hoB = hidden[b1 * H_D + jw];

    // exchange planes
    unsigned long long* const exg0 = ex + (size_t)g * EXG;
    unsigned long long* const exg1 = exg0 + EXP_W;

    // ---- prologue: h_0 -> hs[0][*]; out[:,0,:] = h_0 (one WG per group)
    {
        float vA = hidden[b0 * H_D + tid];
        float vB = hidden[b1 * H_D + tid];
        hs[0][0][tid] = vA;
        hs[0][1][tid] = vB;
        if (wm == 0) {
            out[(size_t)b0 * TH_F + tid] = vA;
            out[(size_t)b1 * TH_F + tid] = vB;
        }
    }
    __syncthreads();

    // x lane-slice pointers + first prefetch (per batch)
    const float4* xpA = (const float4*)(x + (size_t)b0 * TH_F) + lane * 2;
    const float4* xpB = (const float4*)(x + (size_t)b1 * TH_F) + lane * 2;
    float4 xA0 = xpA[0], xA1 = xpA[1];
    float4 xB0 = xpB[0], xB1 = xpB[1];

    unsigned long long pwA = 0, pwB = 0;   // carried early polls

    for (int t = 0; t < T_S; ++t) {
        const bool do_next = (t + 1 < T_S);
        const int  p = t & 1;
        unsigned long long* const exgP  = p ? exg1 : exg0;   // step-t plane
        unsigned long long* const exgNP = p ? exg0 : exg1;   // step-t+1 plane

        //================ PHASE A (batch b0) ================
        float acc[2][3];
        #pragma unroll
        for (int r = 0; r < 2; ++r)
            #pragma unroll
            for (int m = 0; m < 3; ++m) {
                float w0,w1,w2,w3,w4,w5,w6,w7;
                FETCH(w0, awx[r][m][0]); FETCH(w1, awx[r][m][1]);
                FETCH(w2, awx[r][m][2]); FETCH(w3, awx[r][m][3]);
                FETCH(w4, awx[r][m][4]); FETCH(w5, awx[r][m][5]);
                FETCH(w6, awx[r][m][6]); FETCH(w7, awx[r][m][7]);
                float s = 0.f;
                s = fmaf(w0, xA0.x, s); s = fmaf(w1, xA0.y, s);
                s = fmaf(w2, xA0.z, s); s = fmaf(w3, xA0.w, s);
                s = fmaf(w4, xA1.x, s); s = fmaf(w5, xA1.y, s);
                s = fmaf(w6, xA1.z, s); s = fmaf(w7, xA1.w, s);
                acc[r][m] = s;
            }
        if (do_next) {                       // prefetch x_A(t+1)
            const size_t o = (size_t)(t + 1) * 128;
            xA0 = xpA[o]; xA1 = xpA[o + 1];
        }
        if (t > 0) {                         // spin on own word (poll carried)
            const unsigned tt = (unsigned)t;
            while ((unsigned)(pwA >> 32) != tt)
                pwA = __hip_atomic_load(exgP + tid, __ATOMIC_RELAXED,
                                        __HIP_MEMORY_SCOPE_AGENT);
            union { unsigned u; float f; } cv; cv.u = (unsigned)pwA;
            hs[p][0][tid] = cv.f;
            __syncthreads();
        }
        {   // h-part
            const float4* hp = (const float4*)&hs[p][0][0] + lane * 2;
            const float4 h0v = hp[0], h1v = hp[1];
            #pragma unroll
            for (int r = 0; r < 2; ++r)
                #pragma unroll
                for (int m = 0; m < 3; ++m) {
                    float w0,w1,w2,w3,w4,w5,w6,w7;
                    FETCH(w0, awh[r][m][0]); FETCH(w1, awh[r][m][1]);
                    FETCH(w2, awh[r][m][2]); FETCH(w3, awh[r][m][3]);
                    FETCH(w4, awh[r][m][4]); FETCH(w5, awh[r][m][5]);
                    FETCH(w6, awh[r][m][6]); FETCH(w7, awh[r][m][7]);
                    float s = acc[r][m];
                    s = fmaf(w0, h0v.x, s); s = fmaf(w1, h0v.y, s);
                    s = fmaf(w2, h0v.z, s); s = fmaf(w3, h0v.w, s);
                    s = fmaf(w4, h1v.x, s); s = fmaf(w5, h1v.y, s);
                    s = fmaf(w6, h1v.z, s); s = fmaf(w7, h1v.w, s);
                    acc[r][m] = s;
                }
        }
        {   // reduce: row-specialize at xor-1, then full butterfly (18 shfl)
            float a3[3];
            const bool rs = (lane & 1) != 0;
            #pragma unroll
            for (int m = 0; m < 3; ++m) {
                float keep = rs ? acc[1][m] : acc[0][m];
                float send = rs ? acc[0][m] : acc[1][m];
                a3[m] = keep + __shfl_xor(send, 1);
            }
            #pragma unroll
            for (int s = 2; s < 64; s <<= 1) {
                a3[0] += __shfl_xor(a3[0], s);
                a3[1] += __shfl_xor(a3[1], s);
                a3[2] += __shfl_xor(a3[2], s);
            }
            if (lane < 2) {                  // gate + store h_A(t+1)
                const float q = a3[0] + bqw;
                const float k = a3[1] + bkw;
                const float v = a3[2] + bvw;
                const float e  = __expf(-q * k);
                const float w  = __builtin_amdgcn_rcpf(1.f + e);
                const float ev = __expf(2.f * v);
                const float th = 1.f - 2.f * __builtin_amdgcn_rcpf(ev + 1.f);
                const float hn = fmaf(w, th - hoA, hoA);
                if (do_next) {
                    out[(size_t)b0 * TH_F + (size_t)(t + 1) * H_D + jw] = hn;
                    union { float f; unsigned u; } cw; cw.f = hn;
                    __hip_atomic_store(exgNP + jw,
                        (((unsigned long long)(unsigned)(t + 1)) << 32) | cw.u,
                        __ATOMIC_RELAXED, __HIP_MEMORY_SCOPE_AGENT);
                } else {
                    out[NTH + (size_t)b0 * H_D + jw] = hn;   // h_final tail
                }
                hoA = hn;
            }
        }
        if (t > 0) {                         // first-poll-early for phase B
            pwB = __hip_atomic_load(exgP + 512 + tid, __ATOMIC_RELAXED,
                                    __HIP_MEMORY_SCOPE_AGENT);
            asm volatile("" ::: "memory");   // pin the poll here (no sinking)
        }

        //================ PHASE B (batch b1) ================
        #pragma unroll
        for (int r = 0; r < 2; ++r)
            #pragma unroll
            for (int m = 0; m < 3; ++m) {
                float w0,w1,w2,w3,w4,w5,w6,w7;
                FETCH(w0, awx[r][m][0]); FETCH(w1, awx[r][m][1]);
                FETCH(w2, awx[r][m][2]); FETCH(w3, awx[r][m][3]);
                FETCH(w4, awx[r][m][4]); FETCH(w5, awx[r][m][5]);
                FETCH(w6, awx[r][m][6]); FETCH(w7, awx[r][m][7]);
                float s = 0.f;
                s = fmaf(w0, xB0.x, s); s = fmaf(w1, xB0.y, s);
                s = fmaf(w2, xB0.z, s); s = fmaf(w3, xB0.w, s);
                s = fmaf(w4, xB1.x, s); s = fmaf(w5, xB1.y, s);
                s = fmaf(w6, xB1.z, s); s = fmaf(w7, xB1.w, s);
                acc[r][m] = s;
            }
        if (do_next) {                       // prefetch x_B(t+1)
            const size_t o = (size_t)(t + 1) * 128;
            xB0 = xpB[o]; xB1 = xpB[o + 1];
        }
        if (t > 0) {
            const unsigned tt = (unsigned)t;
            while ((unsigned)(pwB >> 32) != tt)
                pwB = __hip_atomic_load(exgP + 512 + tid, __ATOMIC_RELAXED,
                                        __HIP_MEMORY_SCOPE_AGENT);
            union { unsigned u; float f; } cv; cv.u = (unsigned)pwB;
            hs[p][1][tid] = cv.f;
            __syncthreads();
        }
        {   // h-part
            const float4* hp = (const float4*)&hs[p][1][0] + lane * 2;
            const float4 h0v = hp[0], h1v = hp[1];
            #pragma unroll
            for (int r = 0; r < 2; ++r)
                #pragma unroll
                for (int m = 0; m < 3; ++m) {
                    float w0,w1,w2,w3,w4,w5,w6,w7;
                    FETCH(w0, awh[r][m][0]); FETCH(w1, awh[r][m][1]);
                    FETCH(w2, awh[r][m][2]); FETCH(w3, awh[r][m][3]);
                    FETCH(w4, awh[r][m][4]); FETCH(w5, awh[r][m][5]);
                    FETCH(w6, awh[r][m][6]); FETCH(w7, awh[r][m][7]);
                    float s = acc[r][m];
                    s = fmaf(w0, h0v.x, s); s = fmaf(w1, h0v.y, s);
                    s = fmaf(w2, h0v.z, s); s = fmaf(w3, h0v.w, s);
                    s = fmaf(w4, h1v.x, s); s = fmaf(w5, h1v.y, s);
                    s = fmaf(w6, h1v.z, s); s = fmaf(w7, h1v.w, s);
                    acc[r][m] = s;
                }
        }
        {   // reduce + gate + store h_B(t+1)
            float a3[3];
            const bool rs = (lane & 1) != 0;
            #pragma unroll
            for (int m = 0; m < 3; ++m) {
                float keep = rs ? acc[1][m] : acc[0][m];
                float send = rs ? acc[0][m] : acc[1][m];
                a3[m] = keep + __shfl_xor(send, 1);
            }
            #pragma unroll
            for (int s = 2; s < 64; s <<= 1) {
                a3[0] += __shfl_xor(a3[0], s);
                a3[1] += __shfl_xor(a3[1], s);
                a3[2] += __shfl_xor(a3[2], s);
            }
            if (lane < 2) {
                const float q = a3[0] + bqw;
                const float k = a3[1] + bkw;
                const float v = a3[2] + bvw;
                const float e  = __expf(-q * k);
                const float w  = __builtin_amdgcn_rcpf(1.f + e);
                const float ev = __expf(2.f * v);
                const float th = 1.f - 2.f * __builtin_amdgcn_rcpf(ev + 1.f);
                const float hn = fmaf(w, th - hoB, hoB);
                if (do_next) {
                    out[(size_t)b1 * TH_F + (size_t)(t + 1) * H_D + jw] = hn;
                    union { float f; unsigned u; } cw; cw.f = hn;
                    __hip_atomic_store(exgNP + 512 + jw,
                        (((unsigned long long)(unsigned)(t + 1)) << 32) | cw.u,
                        __ATOMIC_RELAXED, __HIP_MEMORY_SCOPE_AGENT);
                } else {
                    out[NTH + (size_t)b1 * H_D + jw] = hn;   // h_final tail
                }
                hoB = hn;
            }
        }
        if (do_next) {                       // first-poll-early for A(t+1)
            pwA = __hip_atomic_load(exgNP + tid, __ATOMIC_RELAXED,
                                    __HIP_MEMORY_SCOPE_AGENT);
            asm volatile("" ::: "memory");
        }
    }
}

extern "C" void kernel_launch(void* const* d_in, const int* in_sizes, int n_in,
                              void* d_out, int out_size, void* d_ws, size_t ws_size,
                              hipStream_t stream) {
    const float* x      = (const float*)d_in[0];
    const float* hidden = (const float*)d_in[1];
    const float* Wq     = (const float*)d_in[2];
    const float* bq     = (const float*)d_in[3];
    const float* Wk     = (const float*)d_in[4];
    const float* bk     = (const float*)d_in[5];
    const float* Wv     = (const float*)d_in[6];
    const float* bv     = (const float*)d_in[7];
    float* out = (float*)d_out;
    unsigned long long* ex = (unsigned long long*)d_ws;  // 2 x 8 x 1024 words

    // Clear tags every call (replay-safe: stale tags would satisfy spins).
    hipMemsetAsync(ex, 0, 2 * EXP_W * sizeof(unsigned long long), stream);

    void* args[] = { (void*)&x, (void*)&hidden,
                     (void*)&Wq, (void*)&bq, (void*)&Wk, (void*)&bk,
                     (void*)&Wv, (void*)&bv, (void*)&out, (void*)&ex };
    hipLaunchCooperativeKernel((const void*)rnn_persist,
                               dim3(NGROUP * WPG), dim3(THREADS),
                               args, 0, stream);
}

// Round 12
// 6700.188 us; speedup vs baseline: 1.0626x; 1.0626x over previous
//
#include <hip/hip_runtime.h>

// AttentionRnnBlock: N=16, T=2048, H=512.
// q|k|v = cat(x_t,h_t) @ W?.T + b? ; w=sigmoid(q*k); h' = (1-w)h + w tanh(v)
//
// Persistent cooperative kernel, 256 WGs x 512 threads, 1 WG/CU.
// 8 groups x 32 WGs; group g owns batches {2g,2g+1}. Round-6 base topology
// (best measured: one spin + one barrier per step) with two new levers:
//
//  1) fp16 compute path: weights packed to 48 f16x2 words in AGPRs
//     (v_accvgpr stash, proven round 6); 96 v_dot2_f32_f16 (2 MAC/instr,
//     fp32 accum) replace 192 v_fma_f32; x cvt'd on the fly (8 cvt_pkrtz).
//     h_old / gate / reduce / out all stay fp32.
//  2) halved exchange: ONE tagged word per row, (t+1)<<32|hA_f16|hB_f16<<16,
//     parity planes ex[t&1][g][512] (round-8-proven deadlock-free WAR chain),
//     relaxed agent atomics, data-is-signal, one 512-thread spin + ONE
//     barrier per step (round 10: each extra spin->barrier costs a
//     max-of-512 RTT jitter ~0.6us).
//
// (Round 11 failed to compile: cvt_pkrtz returns vector of __fp16, not
//  _Float16 — all packed types are __fp16 now.)
#define N_B 16
#define T_S 2048
#define H_D 512
#define TH_F ((size_t)T_S * H_D)
#define NTH ((size_t)N_B * TH_F)
#define NGROUP 8
#define WPG 32
#define THREADS 512
#define PLANE_W (NGROUP * H_D)          // 4096 words per parity plane

typedef __fp16 f16x2 __attribute__((ext_vector_type(2)));
union UH { unsigned u; f16x2 h; };
union US { unsigned short s; __fp16 f; };

#define STASHU(dst, src) asm volatile("v_accvgpr_write_b32 %0, %1" : "=a"(dst) : "v"(src))
#define FETCHU(dst, src) asm volatile("v_accvgpr_read_b32 %0, %1" : "=v"(dst) : "a"(src))

#if __has_builtin(__builtin_amdgcn_fdot2)
#define DOT2(a, b, c) __builtin_amdgcn_fdot2((a), (b), (c), false)
#else
#define DOT2(a, b, c) fmaf((float)(a).x, (float)(b).x, fmaf((float)(a).y, (float)(b).y, (c)))
#endif

__global__ __launch_bounds__(THREADS, 1) void rnn_persist(
    const float* __restrict__ x,
    const float* __restrict__ hidden,
    const float* __restrict__ Wq, const float* __restrict__ bq,
    const float* __restrict__ Wk, const float* __restrict__ bk,
    const float* __restrict__ Wv, const float* __restrict__ bv,
    float* __restrict__ out,
    unsigned long long* __restrict__ ex)
{
    const int tid  = threadIdx.x;
    const int lane = tid & 63;
    const int wv   = tid >> 6;          // wave 0..7
    const int g    = blockIdx.x & 7;    // group
    const int wm   = blockIdx.x >> 3;   // member 0..31
    const int b0 = 2 * g, b1 = 2 * g + 1;
    const int jA = wm * 16 + 2 * wv;

    __shared__ __align__(16) __fp16 hs[2][2][H_D];   // [parity][batch][H], 4 KB

    // ---- pack weights to fp16 pairs, stash 48 words in AGPRs
    unsigned awx[2][3][4], awh[2][3][4];
    #pragma unroll
    for (int r = 0; r < 2; ++r) {
        const int j = jA + r;
        #pragma unroll
        for (int m = 0; m < 3; ++m) {
            const float* W = (m == 0) ? Wq : (m == 1) ? Wk : Wv;
            const float* base = W + (size_t)j * 1024 + lane * 8;
            float4 x0 = *(const float4*)(base);
            float4 x1 = *(const float4*)(base + 4);
            float4 h0 = *(const float4*)(base + 512);
            float4 h1 = *(const float4*)(base + 516);
            UH p;
            p.h = __builtin_amdgcn_cvt_pkrtz(x0.x, x0.y); STASHU(awx[r][m][0], p.u);
            p.h = __builtin_amdgcn_cvt_pkrtz(x0.z, x0.w); STASHU(awx[r][m][1], p.u);
            p.h = __builtin_amdgcn_cvt_pkrtz(x1.x, x1.y); STASHU(awx[r][m][2], p.u);
            p.h = __builtin_amdgcn_cvt_pkrtz(x1.z, x1.w); STASHU(awx[r][m][3], p.u);
            p.h = __builtin_amdgcn_cvt_pkrtz(h0.x, h0.y); STASHU(awh[r][m][0], p.u);
            p.h = __builtin_amdgcn_cvt_pkrtz(h0.z, h0.w); STASHU(awh[r][m][1], p.u);
            p.h = __builtin_amdgcn_cvt_pkrtz(h1.x, h1.y); STASHU(awh[r][m][2], p.u);
            p.h = __builtin_amdgcn_cvt_pkrtz(h1.z, h1.w); STASHU(awh[r][m][3], p.u);
        }
    }

    // writer-lane (lane<4) constants: bit0 = batch, bit1 = row
    const int jw = jA + ((lane >> 1) & 1);
    const int bw = (lane & 1) ? b1 : b0;
    const float bqw = bq[jw], bkw = bk[jw], bvw = bv[jw];
    float ho = hidden[bw * H_D + jw];

    // ---- prologue: h_0 -> hs[0] (fp16); out[:,0,:] = h_0 (first WG only)
    {
        float hA = hidden[b0 * H_D + tid];
        float hB = hidden[b1 * H_D + tid];
        hs[0][0][tid] = (__fp16)hA;
        hs[0][1][tid] = (__fp16)hB;
        if (wm == 0) {
            out[(size_t)b0 * TH_F + tid] = hA;
            out[(size_t)b1 * TH_F + tid] = hB;
        }
    }
    __syncthreads();

    // x lane-slice pointers + first prefetch (fp32; packed at use)
    const float4* xpA = (const float4*)(x + (size_t)b0 * TH_F) + lane * 2;
    const float4* xpB = (const float4*)(x + (size_t)b1 * TH_F) + lane * 2;
    float4 xA0 = xpA[0], xA1 = xpA[1];
    float4 xB0 = xpB[0], xB1 = xpB[1];

    for (int t = 0; t < T_S; ++t) {
        const bool do_next = (t + 1 < T_S);
        const int  p = t & 1;
        unsigned long long* const spin = ex + (size_t)p * PLANE_W + g * H_D + tid;

        // ---- early poll (latency hides under x-part)
        unsigned long long w = 0;
        if (t > 0) {
            w = __hip_atomic_load(spin, __ATOMIC_RELAXED, __HIP_MEMORY_SCOPE_AGENT);
            asm volatile("" ::: "memory");
        }

        // ---- pack x_t to fp16 pairs (8 cvt ops)
        UH xk[2][4];
        xk[0][0].h = __builtin_amdgcn_cvt_pkrtz(xA0.x, xA0.y);
        xk[0][1].h = __builtin_amdgcn_cvt_pkrtz(xA0.z, xA0.w);
        xk[0][2].h = __builtin_amdgcn_cvt_pkrtz(xA1.x, xA1.y);
        xk[0][3].h = __builtin_amdgcn_cvt_pkrtz(xA1.z, xA1.w);
        xk[1][0].h = __builtin_amdgcn_cvt_pkrtz(xB0.x, xB0.y);
        xk[1][1].h = __builtin_amdgcn_cvt_pkrtz(xB0.z, xB0.w);
        xk[1][2].h = __builtin_amdgcn_cvt_pkrtz(xB1.x, xB1.y);
        xk[1][3].h = __builtin_amdgcn_cvt_pkrtz(xB1.z, xB1.w);

        // ---- x-part: 24 AGPR fetches + 48 dot2 (h-independent)
        float acc[2][3][2];
        #pragma unroll
        for (int r = 0; r < 2; ++r)
            #pragma unroll
            for (int m = 0; m < 3; ++m) {
                UH w0, w1, w2, w3;
                FETCHU(w0.u, awx[r][m][0]); FETCHU(w1.u, awx[r][m][1]);
                FETCHU(w2.u, awx[r][m][2]); FETCHU(w3.u, awx[r][m][3]);
                float s0 = 0.f, s1 = 0.f;
                s0 = DOT2(w0.h, xk[0][0].h, s0); s1 = DOT2(w0.h, xk[1][0].h, s1);
                s0 = DOT2(w1.h, xk[0][1].h, s0); s1 = DOT2(w1.h, xk[1][1].h, s1);
                s0 = DOT2(w2.h, xk[0][2].h, s0); s1 = DOT2(w2.h, xk[1][2].h, s1);
                s0 = DOT2(w3.h, xk[0][3].h, s0); s1 = DOT2(w3.h, xk[1][3].h, s1);
                acc[r][m][0] = s0; acc[r][m][1] = s1;
            }

        // ---- prefetch x_{t+1} (in flight across the wait)
        if (do_next) {
            const size_t o = (size_t)(t + 1) * 128;
            xA0 = xpA[o]; xA1 = xpA[o + 1];
            xB0 = xpB[o]; xB1 = xpB[o + 1];
        }

        // ---- spin on own tagged word; stage fp16 pair; ONE barrier
        if (t > 0) {
            const unsigned tt = (unsigned)t;
            while ((unsigned)(w >> 32) != tt)
                w = __hip_atomic_load(spin, __ATOMIC_RELAXED, __HIP_MEMORY_SCOPE_AGENT);
            US lo, hi;
            lo.s = (unsigned short)(w & 0xFFFFu);
            hi.s = (unsigned short)((w >> 16) & 0xFFFFu);
            hs[p][0][tid] = lo.f;
            hs[p][1][tid] = hi.f;
            __syncthreads();
        }

        // ---- h-part: 24 AGPR fetches + 48 dot2 (lane-contiguous 16B LDS reads)
        uint4 hA4 = ((const uint4*)&hs[p][0][0])[lane];
        uint4 hB4 = ((const uint4*)&hs[p][1][0])[lane];
        UH hk[2][4];
        hk[0][0].u = hA4.x; hk[0][1].u = hA4.y; hk[0][2].u = hA4.z; hk[0][3].u = hA4.w;
        hk[1][0].u = hB4.x; hk[1][1].u = hB4.y; hk[1][2].u = hB4.z; hk[1][3].u = hB4.w;
        #pragma unroll
        for (int r = 0; r < 2; ++r)
            #pragma unroll
            for (int m = 0; m < 3; ++m) {
                UH w0, w1, w2, w3;
                FETCHU(w0.u, awh[r][m][0]); FETCHU(w1.u, awh[r][m][1]);
                FETCHU(w2.u, awh[r][m][2]); FETCHU(w3.u, awh[r][m][3]);
                float s0 = acc[r][m][0], s1 = acc[r][m][1];
                s0 = DOT2(w0.h, hk[0][0].h, s0); s1 = DOT2(w0.h, hk[1][0].h, s1);
                s0 = DOT2(w1.h, hk[0][1].h, s0); s1 = DOT2(w1.h, hk[1][1].h, s1);
                s0 = DOT2(w2.h, hk[0][2].h, s0); s1 = DOT2(w2.h, hk[1][2].h, s1);
                s0 = DOT2(w3.h, hk[0][3].h, s0); s1 = DOT2(w3.h, hk[1][3].h, s1);
                acc[r][m][0] = s0; acc[r][m][1] = s1;
            }

        // ---- split-butterfly reduce: 21 shfl
        const bool lb0 = (lane & 1) != 0;   // batch bit
        const bool lb1 = (lane & 2) != 0;   // row bit
        float a6[2][3];
        #pragma unroll
        for (int r = 0; r < 2; ++r)
            #pragma unroll
            for (int m = 0; m < 3; ++m) {
                float keep = lb0 ? acc[r][m][1] : acc[r][m][0];
                float send = lb0 ? acc[r][m][0] : acc[r][m][1];
                a6[r][m] = keep + __shfl_xor(send, 1);
            }
        float a3[3];
        #pragma unroll
        for (int m = 0; m < 3; ++m) {
            float keep = lb1 ? a6[1][m] : a6[0][m];
            float send = lb1 ? a6[0][m] : a6[1][m];
            a3[m] = keep + __shfl_xor(send, 2);
        }
        #pragma unroll
        for (int s = 4; s < 64; s <<= 1) {
            a3[0] += __shfl_xor(a3[0], s);
            a3[1] += __shfl_xor(a3[1], s);
            a3[2] += __shfl_xor(a3[2], s);
        }

        // ---- gate + stores (writer lanes 0..3; lanes 0,2 store exchange word)
        if (lane < 4) {
            const float q = a3[0] + bqw;
            const float k = a3[1] + bkw;
            const float v = a3[2] + bvw;
            const float e  = __expf(-q * k);
            const float wg = __builtin_amdgcn_rcpf(1.f + e);
            const float ev = __expf(2.f * v);
            const float th = 1.f - 2.f * __builtin_amdgcn_rcpf(ev + 1.f);
            const float hn = fmaf(wg, th - ho, ho);
            if (do_next) {
                out[(size_t)bw * TH_F + (size_t)(t + 1) * H_D + jw] = hn;  // fp32 output
                US h16; h16.f = (__fp16)hn;
                const int partner = __shfl_xor((int)h16.s, 1);   // other batch, same row
                if ((lane & 1) == 0) {
                    const unsigned long long word =
                        (((unsigned long long)(unsigned)(t + 1)) << 32)
                        | (unsigned)h16.s
                        | (((unsigned)partner & 0xFFFFu) << 16);
                    __hip_atomic_store(ex + (size_t)((t + 1) & 1) * PLANE_W + g * H_D + jw,
                                       word, __ATOMIC_RELAXED, __HIP_MEMORY_SCOPE_AGENT);
                }
            } else {
                out[NTH + (size_t)bw * H_D + jw] = hn;            // h_final tail
            }
            ho = hn;
        }
        // no end barrier: parity-buffered ex + hs make it WAR-safe (round 8).
    }
}

extern "C" void kernel_launch(void* const* d_in, const int* in_sizes, int n_in,
                              void* d_out, int out_size, void* d_ws, size_t ws_size,
                              hipStream_t stream) {
    const float* x      = (const float*)d_in[0];
    const float* hidden = (const float*)d_in[1];
    const float* Wq     = (const float*)d_in[2];
    const float* bq     = (const float*)d_in[3];
    const float* Wk     = (const float*)d_in[4];
    const float* bk     = (const float*)d_in[5];
    const float* Wv     = (const float*)d_in[6];
    const float* bv     = (const float*)d_in[7];
    float* out = (float*)d_out;
    unsigned long long* ex = (unsigned long long*)d_ws;  // 2 planes x 4096 words

    // Clear tags every call (replay-safe: stale tags would satisfy spins).
    (void)hipMemsetAsync(ex, 0, 2 * PLANE_W * sizeof(unsigned long long), stream);

    void* args[] = { (void*)&x, (void*)&hidden,
                     (void*)&Wq, (void*)&bq, (void*)&Wk, (void*)&bk,
                     (void*)&Wv, (void*)&bv, (void*)&out, (void*)&ex };
    (void)hipLaunchCooperativeKernel((const void*)rnn_persist,
                                     dim3(NGROUP * WPG), dim3(THREADS),
                                     args, 0, stream);
}

// Round 13
// 4654.389 us; speedup vs baseline: 1.5297x; 1.4395x over previous
//
#include <hip/hip_runtime.h>

// AttentionRnnBlock: N=16, T=2048, H=512.
// q|k|v = cat(x_t,h_t) @ W?.T + b? ; w=sigmoid(q*k); h' = (1-w)h + w tanh(v)
//
// Persistent cooperative kernel, 256 WGs x 512 threads, 1 WG/CU.
// 8 groups x 32 WGs; group g owns batches {2g,2g+1}. Base = round 6
// (best-measured centralized-sync structure). Single change this round:
//
//   COUNTER -> FLAG ARRAY. Round 6's per-step sync used 32 serialized
//   atomic_fetch_add RMWs on ONE word (~700-1000cy at the coherence point).
//   Now: tid0 of WG wm STORES flags[g][wm] = t+1 (distinct words, parallel,
//   no RMW); threads tid<32 each spin on one flag with >= t (monotonic =>
//   deadlock-free under any skew); the barrier combines the 32 detects.
//
// Evidence base: R8/R10/R12 proved distributed per-thread tagged spins are
// strictly worse (max-of-512 poll jitter + fabric congestion); R12 proved
// compute issue is NOT critical path (halved issue, +46% time). h data
// moves as in R6: writers atomic-store h into out[b,t+1,:] (unique address
// per step => no WAR), readers bulk PoC-load after detect.
// Weights: 96 fp32/thread in AGPRs via v_accvgpr (cannot spill).
#define N_B 16
#define T_S 2048
#define H_D 512
#define TH_F ((size_t)T_S * H_D)
#define NTH ((size_t)N_B * TH_F)
#define NGROUP 8
#define WPG 32
#define THREADS 512

#define STASH(dst, src) asm volatile("v_accvgpr_write_b32 %0, %1" : "=a"(dst) : "v"(src))
#define FETCH(dst, src) asm volatile("v_accvgpr_read_b32 %0, %1" : "=v"(dst) : "a"(src))

__global__ __launch_bounds__(THREADS, 1) void rnn_persist(
    const float* __restrict__ x,
    const float* __restrict__ hidden,
    const float* __restrict__ Wq, const float* __restrict__ bq,
    const float* __restrict__ Wk, const float* __restrict__ bk,
    const float* __restrict__ Wv, const float* __restrict__ bv,
    float* __restrict__ out,
    int* __restrict__ flags)
{
    const int tid  = threadIdx.x;
    const int lane = tid & 63;
    const int wv   = tid >> 6;          // wave 0..7
    const int g    = blockIdx.x & 7;    // group
    const int wm   = blockIdx.x >> 3;   // member 0..31
    const int b0 = 2 * g, b1 = 2 * g + 1;
    const int jA = wm * 16 + 2 * wv;

    __shared__ __align__(16) float hs[2][H_D];   // h_t staging, 4 KB

    // ---- load weights once, stash all 96 floats into AGPRs
    float awx[2][3][8], awh[2][3][8];
    #pragma unroll
    for (int r = 0; r < 2; ++r) {
        const int j = jA + r;
        #pragma unroll
        for (int m = 0; m < 3; ++m) {
            const float* W = (m == 0) ? Wq : (m == 1) ? Wk : Wv;
            const float* base = W + (size_t)j * 1024 + lane * 8;
            float4 x0 = *(const float4*)(base);
            float4 x1 = *(const float4*)(base + 4);
            float4 h0 = *(const float4*)(base + 512);
            float4 h1 = *(const float4*)(base + 516);
            STASH(awx[r][m][0], x0.x); STASH(awx[r][m][1], x0.y);
            STASH(awx[r][m][2], x0.z); STASH(awx[r][m][3], x0.w);
            STASH(awx[r][m][4], x1.x); STASH(awx[r][m][5], x1.y);
            STASH(awx[r][m][6], x1.z); STASH(awx[r][m][7], x1.w);
            STASH(awh[r][m][0], h0.x); STASH(awh[r][m][1], h0.y);
            STASH(awh[r][m][2], h0.z); STASH(awh[r][m][3], h0.w);
            STASH(awh[r][m][4], h1.x); STASH(awh[r][m][5], h1.y);
            STASH(awh[r][m][6], h1.z); STASH(awh[r][m][7], h1.w);
        }
    }

    // writer-lane (lane<4) constants: bit0 = batch, bit1 = row
    const int jw = jA + ((lane >> 1) & 1);
    const int bw = (lane & 1) ? b1 : b0;
    const float bqw = bq[jw], bkw = bk[jw], bvw = bv[jw];
    float ho = hidden[bw * H_D + jw];

    // h staging map: thread -> (batch half, float2 #u)
    const int h_nb  = tid >> 8;
    const int u     = tid & 255;
    const int h_pos = u * 2;
    const int h_b   = h_nb ? b1 : b0;

    // ---- prologue: h_0 -> LDS; out[:,0,:] = h_0 (group's first WG only)
    {
        float v0 = hidden[h_b * H_D + h_pos];
        float v1 = hidden[h_b * H_D + h_pos + 1];
        *(float2*)&hs[h_nb][h_pos] = make_float2(v0, v1);
        if (wm == 0) {
            out[(size_t)h_b * TH_F + h_pos]     = v0;
            out[(size_t)h_b * TH_F + h_pos + 1] = v1;
        }
    }
    __syncthreads();

    // x lane-slice pointers (float4 granularity) + first prefetch
    const float4* xb0 = (const float4*)(x + (size_t)b0 * TH_F) + lane * 2;
    const float4* xb1 = (const float4*)(x + (size_t)b1 * TH_F) + lane * 2;
    float ax[2][8];
    {
        float4 a = xb0[0], b = xb0[1], c = xb1[0], d = xb1[1];
        ax[0][0]=a.x; ax[0][1]=a.y; ax[0][2]=a.z; ax[0][3]=a.w;
        ax[0][4]=b.x; ax[0][5]=b.y; ax[0][6]=b.z; ax[0][7]=b.w;
        ax[1][0]=c.x; ax[1][1]=c.y; ax[1][2]=c.z; ax[1][3]=c.w;
        ax[1][4]=d.x; ax[1][5]=d.y; ax[1][6]=d.z; ax[1][7]=d.w;
    }

    int* const fl = flags + g * 64;     // 32 flags, 256B-strided per group

    for (int t = 0; t < T_S; ++t) {
        const bool do_next = (t + 1 < T_S);

        // ---- x-part: 48 AGPR fetches + 96 FMAs — h-independent, runs
        //      before the group wait to hide exchange latency
        float acc[2][3][2];
        #pragma unroll
        for (int r = 0; r < 2; ++r)
            #pragma unroll
            for (int m = 0; m < 3; ++m) {
                float wreg[8];
                #pragma unroll
                for (int c = 0; c < 8; ++c) FETCH(wreg[c], awx[r][m][c]);
                float s0 = 0.f, s1 = 0.f;
                #pragma unroll
                for (int c = 0; c < 8; ++c) {
                    s0 = fmaf(wreg[c], ax[0][c], s0);
                    s1 = fmaf(wreg[c], ax[1][c], s1);
                }
                acc[r][m][0] = s0; acc[r][m][1] = s1;
            }

        // ---- prefetch x_{t+1} (in flight across the wait)
        if (do_next) {
            const size_t o = (size_t)(t + 1) * 128;
            float4 a = xb0[o], b = xb0[o + 1], c = xb1[o], d = xb1[o + 1];
            ax[0][0]=a.x; ax[0][1]=a.y; ax[0][2]=a.z; ax[0][3]=a.w;
            ax[0][4]=b.x; ax[0][5]=b.y; ax[0][6]=b.z; ax[0][7]=b.w;
            ax[1][0]=c.x; ax[1][1]=c.y; ax[1][2]=c.z; ax[1][3]=c.w;
            ax[1][4]=d.x; ax[1][5]=d.y; ax[1][6]=d.z; ax[1][7]=d.w;
        }

        // ---- wait for h_t: 32 parallel single-flag spins (>= t, monotonic,
        //      no RMW), barrier combines; then bulk PoC load -> LDS
        if (t > 0) {
            if (tid < WPG) {
                const int* f = fl + tid;
                while (__hip_atomic_load(f, __ATOMIC_RELAXED,
                                         __HIP_MEMORY_SCOPE_AGENT) < t) {}
            }
            __syncthreads();
            const unsigned long long* hsrc =
                (const unsigned long long*)(out + (size_t)h_b * TH_F + (size_t)t * H_D) + u;
            unsigned long long raw =
                __hip_atomic_load(hsrc, __ATOMIC_RELAXED, __HIP_MEMORY_SCOPE_AGENT);
            union { unsigned long long q; float2 f; } cv; cv.q = raw;
            *(float2*)&hs[h_nb][h_pos] = cv.f;
            __syncthreads();
        }

        // ---- h-part: 48 AGPR fetches + 96 FMAs
        float hbv[2][8];
        #pragma unroll
        for (int nb = 0; nb < 2; ++nb) {
            const float4* hp = (const float4*)&hs[nb][0] + lane * 2;
            float4 a0 = hp[0], a1 = hp[1];
            hbv[nb][0]=a0.x; hbv[nb][1]=a0.y; hbv[nb][2]=a0.z; hbv[nb][3]=a0.w;
            hbv[nb][4]=a1.x; hbv[nb][5]=a1.y; hbv[nb][6]=a1.z; hbv[nb][7]=a1.w;
        }
        #pragma unroll
        for (int r = 0; r < 2; ++r)
            #pragma unroll
            for (int m = 0; m < 3; ++m) {
                float wreg[8];
                #pragma unroll
                for (int c = 0; c < 8; ++c) FETCH(wreg[c], awh[r][m][c]);
                float s0 = acc[r][m][0], s1 = acc[r][m][1];
                #pragma unroll
                for (int c = 0; c < 8; ++c) {
                    s0 = fmaf(wreg[c], hbv[0][c], s0);
                    s1 = fmaf(wreg[c], hbv[1][c], s1);
                }
                acc[r][m][0] = s0; acc[r][m][1] = s1;
            }

        // ---- split-butterfly reduce: 21 shfl
        const bool lb0 = (lane & 1) != 0;   // batch bit
        const bool lb1 = (lane & 2) != 0;   // row bit
        float a6[2][3];
        #pragma unroll
        for (int r = 0; r < 2; ++r)
            #pragma unroll
            for (int m = 0; m < 3; ++m) {
                float keep = lb0 ? acc[r][m][1] : acc[r][m][0];
                float send = lb0 ? acc[r][m][0] : acc[r][m][1];
                a6[r][m] = keep + __shfl_xor(send, 1);
            }
        float a3[3];
        #pragma unroll
        for (int m = 0; m < 3; ++m) {
            float keep = lb1 ? a6[1][m] : a6[0][m];
            float send = lb1 ? a6[0][m] : a6[1][m];
            a3[m] = keep + __shfl_xor(send, 2);
        }
        #pragma unroll
        for (int s = 4; s < 64; s <<= 1) {
            a3[0] += __shfl_xor(a3[0], s);
            a3[1] += __shfl_xor(a3[1], s);
            a3[2] += __shfl_xor(a3[2], s);
        }

        // ---- gate + h_{t+1} store (writer lanes 0..3)
        if (lane < 4) {
            const float q = a3[0] + bqw;
            const float k = a3[1] + bkw;
            const float v = a3[2] + bvw;
            const float e  = __expf(-q * k);
            const float w  = __builtin_amdgcn_rcpf(1.f + e);
            const float ev = __expf(2.f * v);
            const float th = 1.f - 2.f * __builtin_amdgcn_rcpf(ev + 1.f);
            const float hn = fmaf(w, th - ho, ho);
            const size_t opos = do_next
                ? ((size_t)bw * TH_F + (size_t)(t + 1) * H_D + jw)
                : (NTH + (size_t)bw * H_D + jw);            // h_final tail
            __hip_atomic_store(out + opos, hn, __ATOMIC_RELAXED,
                               __HIP_MEMORY_SCOPE_AGENT);
            ho = hn;
        }

        // ---- signal: drain all waves' h stores (barrier), then flag STORE
        //      (parallel across WGs — no RMW serialization)
        __syncthreads();
        if (do_next && tid == 0)
            __hip_atomic_store(fl + wm, t + 1, __ATOMIC_RELAXED,
                               __HIP_MEMORY_SCOPE_AGENT);
    }
}

extern "C" void kernel_launch(void* const* d_in, const int* in_sizes, int n_in,
                              void* d_out, int out_size, void* d_ws, size_t ws_size,
                              hipStream_t stream) {
    const float* x      = (const float*)d_in[0];
    const float* hidden = (const float*)d_in[1];
    const float* Wq     = (const float*)d_in[2];
    const float* bq     = (const float*)d_in[3];
    const float* Wk     = (const float*)d_in[4];
    const float* bk     = (const float*)d_in[5];
    const float* Wv     = (const float*)d_in[6];
    const float* bv     = (const float*)d_in[7];
    float* out = (float*)d_out;
    int*   flags = (int*)d_ws;   // 8 groups x 64-int stride (32 used)

    // Clear flags every call (replay-safe: stale flags would satisfy spins).
    (void)hipMemsetAsync(flags, 0, NGROUP * 64 * sizeof(int), stream);

    void* args[] = { (void*)&x, (void*)&hidden,
                     (void*)&Wq, (void*)&bq, (void*)&Wk, (void*)&bk,
                     (void*)&Wv, (void*)&bv, (void*)&out, (void*)&flags };
    (void)hipLaunchCooperativeKernel((const void*)rnn_persist,
                                     dim3(NGROUP * WPG), dim3(THREADS),
                                     args, 0, stream);
}

// Round 14
// 4265.505 us; speedup vs baseline: 1.6691x; 1.0912x over previous
//
#include <hip/hip_runtime.h>

// AttentionRnnBlock: N=16, T=2048, H=512.
// q|k|v = cat(x_t,h_t) @ W?.T + b? ; w=sigmoid(q*k); h' = (1-w)h + w tanh(v)
//
// Persistent cooperative kernel, 256 WGs x 512 threads, 1 WG/CU.
// 8 groups x 32 WGs; group g owns batches {2g,2g+1}.
//
// BASE = ROUND 4 (best measured: 4266 us). Rounds 5-13 established:
//  - AGPR weight pinning: null (R6). fp16 dot2 (halved issue): -46% (R12).
//  - flag-array vs counter RMW: null (R13). distributed tagged spins: worse
//    (R8/R10/R12). L2-local coherence tricks: hang (R9). The step time is a
//    serial chain of ~2 agent-scope RTTs + barriers; sync mechanism choice
//    is ~irrelevant. So: revert to R4 exactly.
//
// SINGLE CHANGE vs R4: conflict-free lane slice remap. R4's h-part LDS
// reads were float4 pairs at lane*32B -> 8-way bank conflict (the invariant
// SQ_LDS_BANK_CONFLICT = 2^26 = ~128cy/WG/step). Now each lane owns
// {[4L,4L+4), [256+4L,+4)} of each cat half: ds_read_b128 at byte offsets
// 16L and 1024+16L -> perfect 32-bank spread, 0 conflicts. Weight-load
// offsets remapped to match; reduce/writers/sync identical to R4.
#define N_B 16
#define T_S 2048
#define H_D 512
#define TH_F ((size_t)T_S * H_D)
#define NTH ((size_t)N_B * TH_F)
#define NGROUP 8
#define WPG 32
#define THREADS 512

__global__ __launch_bounds__(THREADS, 1) void rnn_persist(
    const float* __restrict__ x,
    const float* __restrict__ hidden,
    const float* __restrict__ Wq, const float* __restrict__ bq,
    const float* __restrict__ Wk, const float* __restrict__ bk,
    const float* __restrict__ Wv, const float* __restrict__ bv,
    float* __restrict__ out,
    int* __restrict__ cnt)
{
    const int tid  = threadIdx.x;
    const int lane = tid & 63;
    const int wv   = tid >> 6;          // wave 0..7
    const int g    = blockIdx.x & 7;    // group
    const int wm   = blockIdx.x >> 3;   // member 0..31
    const int b0 = 2 * g, b1 = 2 * g + 1;
    const int jA = wm * 16 + 2 * wv;

    __shared__ __align__(16) float hs[2][H_D];   // h_t staging, 4 KB

    // ---- weights: lane owns cat slices {[4L,4L+4), [256+4L,+4)} per half.
    //      (conflict-free remap; compiler streams these from L2 each step —
    //       measured faster than AGPR pinning, see R4 vs R6/R13.)
    float4 wx[2][3][2], wh[2][3][2];
    #pragma unroll
    for (int r = 0; r < 2; ++r) {
        const int j = jA + r;
        #pragma unroll
        for (int m = 0; m < 3; ++m) {
            const float* W = (m == 0) ? Wq : (m == 1) ? Wk : Wv;
            const float* base = W + (size_t)j * 1024 + lane * 4;
            wx[r][m][0] = *(const float4*)(base);
            wx[r][m][1] = *(const float4*)(base + 256);
            wh[r][m][0] = *(const float4*)(base + 512);
            wh[r][m][1] = *(const float4*)(base + 768);
        }
    }

    // writer-lane (lane<4) constants: bit0 = batch, bit1 = row
    const int jw = jA + ((lane >> 1) & 1);
    const int bw = (lane & 1) ? b1 : b0;
    const float bqw = bq[jw], bkw = bk[jw], bvw = bv[jw];
    float ho = hidden[bw * H_D + jw];

    // h staging map: thread -> (batch half, float2 #u)
    const int h_nb  = tid >> 8;
    const int u     = tid & 255;
    const int h_pos = u * 2;
    const int h_b   = h_nb ? b1 : b0;

    // ---- prologue: h_0 -> LDS; out[:,0,:] = h_0 (group's first WG only)
    {
        float v0 = hidden[h_b * H_D + h_pos];
        float v1 = hidden[h_b * H_D + h_pos + 1];
        *(float2*)&hs[h_nb][h_pos] = make_float2(v0, v1);
        if (wm == 0) {
            out[(size_t)h_b * TH_F + h_pos]     = v0;
            out[(size_t)h_b * TH_F + h_pos + 1] = v1;
        }
    }
    __syncthreads();

    // x lane-slice pointers (float4 granularity, remapped) + first prefetch
    const float4* xq0 = (const float4*)(x + (size_t)b0 * TH_F);
    const float4* xq1 = (const float4*)(x + (size_t)b1 * TH_F);
    float4 xv[2][2];
    xv[0][0] = xq0[lane]; xv[0][1] = xq0[64 + lane];
    xv[1][0] = xq1[lane]; xv[1][1] = xq1[64 + lane];

    int* mycnt = cnt + g * 64;   // 256B-strided per-group counter

    for (int t = 0; t < T_S; ++t) {
        const bool do_next = (t + 1 < T_S);

        // ---- x-part FMAs (96) — h-independent, hides exchange latency
        float acc[2][3][2];
        #pragma unroll
        for (int r = 0; r < 2; ++r)
            #pragma unroll
            for (int m = 0; m < 3; ++m)
                #pragma unroll
                for (int nb = 0; nb < 2; ++nb) acc[r][m][nb] = 0.f;

        #pragma unroll
        for (int nb = 0; nb < 2; ++nb) {
            const float4 a0 = nb ? xv[1][0] : xv[0][0];
            const float4 a1 = nb ? xv[1][1] : xv[0][1];
            #pragma unroll
            for (int r = 0; r < 2; ++r)
                #pragma unroll
                for (int m = 0; m < 3; ++m) {
                    float s = acc[r][m][nb];
                    s = fmaf(wx[r][m][0].x, a0.x, s);
                    s = fmaf(wx[r][m][0].y, a0.y, s);
                    s = fmaf(wx[r][m][0].z, a0.z, s);
                    s = fmaf(wx[r][m][0].w, a0.w, s);
                    s = fmaf(wx[r][m][1].x, a1.x, s);
                    s = fmaf(wx[r][m][1].y, a1.y, s);
                    s = fmaf(wx[r][m][1].z, a1.z, s);
                    s = fmaf(wx[r][m][1].w, a1.w, s);
                    acc[r][m][nb] = s;
                }
        }

        // ---- prefetch x_{t+1} (in flight across the wait)
        if (do_next) {
            const size_t o = (size_t)(t + 1) * 128;
            xv[0][0] = xq0[o + lane]; xv[0][1] = xq0[o + 64 + lane];
            xv[1][0] = xq1[o + lane]; xv[1][1] = xq1[o + 64 + lane];
        }

        // ---- wait for h_t, stage into LDS (t>=1; t=0 staged in prologue)
        if (t > 0) {
            if (tid == 0) {
                const int target = WPG * t;
                while (__hip_atomic_load(mycnt, __ATOMIC_RELAXED,
                                         __HIP_MEMORY_SCOPE_AGENT) < target) {}
            }
            __syncthreads();
            const float* hsrc = out + (size_t)h_b * TH_F + (size_t)t * H_D + h_pos;
            float v0 = __hip_atomic_load(hsrc,     __ATOMIC_RELAXED, __HIP_MEMORY_SCOPE_AGENT);
            float v1 = __hip_atomic_load(hsrc + 1, __ATOMIC_RELAXED, __HIP_MEMORY_SCOPE_AGENT);
            *(float2*)&hs[h_nb][h_pos] = make_float2(v0, v1);
            __syncthreads();
        }

        // ---- h-part FMAs (96): b128 reads at 16L and 1024+16L — 0 conflicts
        #pragma unroll
        for (int nb = 0; nb < 2; ++nb) {
            const float4* h4 = (const float4*)&hs[nb][0];
            const float4 a0 = h4[lane];
            const float4 a1 = h4[64 + lane];
            #pragma unroll
            for (int r = 0; r < 2; ++r)
                #pragma unroll
                for (int m = 0; m < 3; ++m) {
                    float s = acc[r][m][nb];
                    s = fmaf(wh[r][m][0].x, a0.x, s);
                    s = fmaf(wh[r][m][0].y, a0.y, s);
                    s = fmaf(wh[r][m][0].z, a0.z, s);
                    s = fmaf(wh[r][m][0].w, a0.w, s);
                    s = fmaf(wh[r][m][1].x, a1.x, s);
                    s = fmaf(wh[r][m][1].y, a1.y, s);
                    s = fmaf(wh[r][m][1].z, a1.z, s);
                    s = fmaf(wh[r][m][1].w, a1.w, s);
                    acc[r][m][nb] = s;
                }
        }

        // ---- split-butterfly reduce: 21 shfl instead of 72
        const bool lb0 = (lane & 1) != 0;   // batch bit
        const bool lb1 = (lane & 2) != 0;   // row bit
        float a6[2][3];
        #pragma unroll
        for (int r = 0; r < 2; ++r)
            #pragma unroll
            for (int m = 0; m < 3; ++m) {
                float keep = lb0 ? acc[r][m][1] : acc[r][m][0];
                float send = lb0 ? acc[r][m][0] : acc[r][m][1];
                a6[r][m] = keep + __shfl_xor(send, 1);
            }
        float a3[3];
        #pragma unroll
        for (int m = 0; m < 3; ++m) {
            float keep = lb1 ? a6[1][m] : a6[0][m];
            float send = lb1 ? a6[0][m] : a6[1][m];
            a3[m] = keep + __shfl_xor(send, 2);
        }
        #pragma unroll
        for (int s = 4; s < 64; s <<= 1) {
            a3[0] += __shfl_xor(a3[0], s);
            a3[1] += __shfl_xor(a3[1], s);
            a3[2] += __shfl_xor(a3[2], s);
        }

        // ---- gate + h_{t+1} store (writer lanes 0..3)
        if (lane < 4) {
            const float q = a3[0] + bqw;
            const float k = a3[1] + bkw;
            const float v = a3[2] + bvw;
            const float e  = __expf(-q * k);
            const float w  = __builtin_amdgcn_rcpf(1.f + e);
            const float ev = __expf(2.f * v);
            const float th = 1.f - 2.f * __builtin_amdgcn_rcpf(ev + 1.f);
            const float hn = fmaf(w, th - ho, ho);
            const size_t opos = do_next
                ? ((size_t)bw * TH_F + (size_t)(t + 1) * H_D + jw)
                : (NTH + (size_t)bw * H_D + jw);            // h_final tail
            __hip_atomic_store(out + opos, hn, __ATOMIC_RELAXED,
                               __HIP_MEMORY_SCOPE_AGENT);
            ho = hn;
        }

        // ---- signal: all 8 waves' stores drained (barrier), then +1
        __syncthreads();
        if (do_next && tid == 0)
            __hip_atomic_fetch_add(mycnt, 1, __ATOMIC_RELAXED,
                                   __HIP_MEMORY_SCOPE_AGENT);
    }
}

extern "C" void kernel_launch(void* const* d_in, const int* in_sizes, int n_in,
                              void* d_out, int out_size, void* d_ws, size_t ws_size,
                              hipStream_t stream) {
    const float* x      = (const float*)d_in[0];
    const float* hidden = (const float*)d_in[1];
    const float* Wq     = (const float*)d_in[2];
    const float* bq     = (const float*)d_in[3];
    const float* Wk     = (const float*)d_in[4];
    const float* bk     = (const float*)d_in[5];
    const float* Wv     = (const float*)d_in[6];
    const float* bv     = (const float*)d_in[7];
    float* out = (float*)d_out;
    int*   cnt = (int*)d_ws;   // 8 counters, 256B stride

    (void)hipMemsetAsync(cnt, 0, 16 * 64 * sizeof(int), stream);

    void* args[] = { (void*)&x, (void*)&hidden,
                     (void*)&Wq, (void*)&bq, (void*)&Wk, (void*)&bk,
                     (void*)&Wv, (void*)&bv, (void*)&out, (void*)&cnt };
    (void)hipLaunchCooperativeKernel((const void*)rnn_persist,
                                     dim3(NGROUP * WPG), dim3(THREADS),
                                     args, 0, stream);
}